// Round 9
// baseline (654.356 us; speedup 1.0000x reference)
//
#include <hip/hip_runtime.h>

// ---------------------------------------------------------------------------
// RoPE attention: out = softmax(mask(RoPE(xWq^T) @ RoPE(xWk^T)^T / sqrt(d))) @ (xWv^T)
// B=4, T=2048, d=1024. fp32 in/out, bf16 MFMA internally.
// R8 -> R9: __launch_bounds__(256, 2) on the three GEMM kernels. R8's BK=64
// spilled (WRITE_SIZE 75->480 MB, SGPR 32->112, MfmaUtil 23->8.5%): 32 prefetch
// + 64 acc + 32 frag VGPRs exceeded the default high-occupancy register cap.
// 2 waves/EU -> ~256-reg budget -> no spill. Everything else identical to R8
// so the BK=64 barrier-halving hypothesis gets an unconfounded test.
// ---------------------------------------------------------------------------

typedef float f32x4 __attribute__((ext_vector_type(4)));
typedef __bf16 bf16x8 __attribute__((ext_vector_type(8)));

#define BM 128
#define BN 128
#define BK 64  // ushorts per row in LDS tile; 128x64x2B = 16 KB per buffer

__device__ __forceinline__ unsigned short f2bf(float f) {
  union { float f; unsigned int u; } c; c.f = f;
  unsigned int u = c.u;
  u += 0x7fffu + ((u >> 16) & 1u);  // round-nearest-even
  return (unsigned short)(u >> 16);
}
__device__ __forceinline__ float bf2f(unsigned short h) {
  union { unsigned int u; float f; } c; c.u = ((unsigned int)h) << 16;
  return c.f;
}

// ---------------------------------------------------------------------------
// All fp32->bf16 casts in one kernel; last block zeroes rowsums.
__global__ __launch_bounds__(256) void cvt_all(
    const float4* __restrict__ x, const float4* __restrict__ wq,
    const float4* __restrict__ wk, const float4* __restrict__ wv,
    ushort4* __restrict__ xb, ushort4* __restrict__ wb,
    float4* __restrict__ rowsums) {
  int b = blockIdx.x, t = threadIdx.x;
  if (b == 11264) {  // zero rowsums: 4*2048 fp32 = 2048 float4
#pragma unroll
    for (int i = 0; i < 8; ++i) rowsums[i * 256 + t] = float4{0.f, 0.f, 0.f, 0.f};
    return;
  }
  const float4* src;
  ushort4* dst;
  long i;
  if (b < 8192) { src = x; dst = xb; i = (long)b * 256 + t; }
  else if (b < 9216) { src = wq; dst = wb; i = (long)(b - 8192) * 256 + t; }
  else if (b < 10240) { src = wk; dst = wb + 262144; i = (long)(b - 9216) * 256 + t; }
  else { src = wv; dst = wb + 524288; i = (long)(b - 10240) * 256 + t; }
  float4 v = src[i];
  ushort4 o;
  o.x = f2bf(v.x); o.y = f2bf(v.y); o.z = f2bf(v.z); o.w = f2bf(v.w);
  dst[i] = o;
}

// ---------------------------------------------------------------------------
// Pipelined NT-GEMM K-loop, BK=64: C[m,n] = sum_k A[m,k]*B[n,k]. 128x128 tile,
// 4 waves (2x2), each 64x64 via 4x4 frags of mfma_f32_16x16x32_bf16, two
// k-steps of 32 per LDS tile. XOR swizzle: 16-B granule g of row r lives at
// granule position g ^ (r & 7)  (conflict-free staging writes + frag reads).
__device__ __forceinline__ void gemm_body(
    const unsigned short* __restrict__ A, const unsigned short* __restrict__ B,
    unsigned short* As, unsigned short* Bs,
    int lda, int ldb, int m0, int n0, int ktiles,
    int tid, int lane, int wave, f32x4 acc[4][4]) {
  const int wm = (wave >> 1) * 64;
  const int wn = (wave & 1) * 64;
  const int srow = tid >> 3;  // 0..31 (+32p)
  const int sc = tid & 7;     // 16-B granule within 128-B row
  const int wbase = srow * 64 + ((sc ^ (srow & 7)) << 3);  // (srow+32p)&7 invariant
  const long ga = (long)(m0 + srow) * lda + (sc << 3);
  const long gb = (long)(n0 + srow) * ldb + (sc << 3);
  const int fm = lane & 15;
  const int q = lane >> 4;

  uint4 a[4], b[4];
#pragma unroll
  for (int p = 0; p < 4; ++p) {
    a[p] = *(const uint4*)&A[ga + (long)p * 32 * lda];
    b[p] = *(const uint4*)&B[gb + (long)p * 32 * ldb];
  }

  for (int kt = 0; kt < ktiles; ++kt) {
    __syncthreads();  // prior frag reads done before overwrite
#pragma unroll
    for (int p = 0; p < 4; ++p) {
      *(uint4*)&As[wbase + p * 2048] = a[p];
      *(uint4*)&Bs[wbase + p * 2048] = b[p];
    }
    __syncthreads();

    // prefetch next tile (clamped on last iter; redundant reload is harmless)
    long ko = (long)((kt + 1 < ktiles) ? kt + 1 : kt) * BK;
#pragma unroll
    for (int p = 0; p < 4; ++p) {
      a[p] = *(const uint4*)&A[ga + (long)p * 32 * lda + ko];
      b[p] = *(const uint4*)&B[gb + (long)p * 32 * ldb + ko];
    }

#pragma unroll
    for (int s = 0; s < 2; ++s) {  // two k-steps of 32
      bf16x8 af[4], bfr[4];
#pragma unroll
      for (int i = 0; i < 4; ++i) {
        int row = wm + i * 16 + fm;
        af[i] = *(const bf16x8*)&As[row * 64 + (((((s << 2) | q)) ^ (row & 7)) << 3)];
      }
#pragma unroll
      for (int j = 0; j < 4; ++j) {
        int row = wn + j * 16 + fm;
        bfr[j] = *(const bf16x8*)&Bs[row * 64 + (((((s << 2) | q)) ^ (row & 7)) << 3)];
      }
#pragma unroll
      for (int i = 0; i < 4; ++i)
#pragma unroll
        for (int j = 0; j < 4; ++j)
          acc[i][j] = __builtin_amdgcn_mfma_f32_16x16x32_bf16(af[i], bfr[j], acc[i][j], 0, 0, 0);
    }
  }
}

// ---------------------------------------------------------------------------
// QKV projection + RoPE. A=xb[8192x1024], B=Wb[3072x1024]. Grid (bm=64, bn=24).
__global__ __launch_bounds__(256, 2) void qkv_rope_gemm(
    const unsigned short* __restrict__ A, const unsigned short* __restrict__ B,
    unsigned short* __restrict__ Qr, unsigned short* __restrict__ Kr,
    unsigned short* __restrict__ Vt) {
  __shared__ __align__(16) unsigned short As[BM * BK];
  __shared__ __align__(16) unsigned short Bs[BN * BK];
  const int tid = threadIdx.x, lane = tid & 63, wave = tid >> 6;
  const int bm = blockIdx.x, bn = blockIdx.y;
  const int m0 = bm * BM, n0 = bn * BN;
  const int wm = (wave >> 1) * 64, wn = (wave & 1) * 64;
  const int q = lane >> 4, fm = lane & 15;

  f32x4 acc[4][4];
#pragma unroll
  for (int i = 0; i < 4; ++i)
#pragma unroll
    for (int j = 0; j < 4; ++j) acc[i][j] = (f32x4)(0.f);

  gemm_body(A, B, As, Bs, 1024, 1024, m0, n0, 16, tid, lane, wave, acc);

  if (n0 < 2048) {
    // Q or K: RoPE (pair (2c,2c+1) in adjacent lanes), chained angle addition:
    // 6 sincos per j; per-element rotation by precomputed delta (r:+1, i:+16).
    const float NEG = -13.287712379549449f / 1024.f;  // -log2(1e4)/1024
    unsigned short* dst = (n0 < 1024) ? Qr : Kr;
    const int t00 = (m0 + wm + q * 4) & 2047;  // no wrap within a block
#pragma unroll
    for (int j = 0; j < 4; ++j) {
      int c = (n0 & 1023) + wn + j * 16 + fm;
      float th = exp2f((float)(c & ~1) * NEG);
      float sgn = (c & 1) ? 1.f : -1.f;
      float ang0 = (float)t00 * th;
      float cb = __cosf(ang0), sb = __sinf(ang0);
      float c1 = __cosf(th), s1 = __sinf(th);
      float c16 = __cosf(16.f * th), s16 = __sinf(16.f * th);
#pragma unroll
      for (int i = 0; i < 4; ++i) {
        int gmB = m0 + wm + i * 16 + q * 4;
        float cr = cb, sr = sb;
#pragma unroll
        for (int r = 0; r < 4; ++r) {
          float v = acc[i][j][r];
          float p = __shfl_xor(v, 1);
          dst[(long)(gmB + r) * 1024 + c] = f2bf(v * cr + sgn * p * sr);
          float crn = cr * c1 - sr * s1;
          sr = sr * c1 + cr * s1;
          cr = crn;
        }
        float cbn = cb * c16 - sb * s16;
        sb = sb * c16 + cb * s16;
        cb = cbn;
      }
    }
  } else {
    // V: transpose to Vt[b][c][t]; 4 consecutive t per lane -> 8-B stores
    const int c0 = n0 - 2048;
#pragma unroll
    for (int j = 0; j < 4; ++j) {
      int c = c0 + wn + j * 16 + fm;
#pragma unroll
      for (int i = 0; i < 4; ++i) {
        int gmB = m0 + wm + i * 16 + q * 4;
        int b = gmB >> 11, t = gmB & 2047;
        ushort4 pk;
        pk.x = f2bf(acc[i][j][0]);
        pk.y = f2bf(acc[i][j][1]);
        pk.z = f2bf(acc[i][j][2]);
        pk.w = f2bf(acc[i][j][3]);
        *(ushort4*)&Vt[((long)b * 1024 + c) * 2048 + t] = pk;
      }
    }
  }
}

// ---------------------------------------------------------------------------
// E = exp(mask(Qr@Kr^T)/32) per batch (z), bf16, + rowsums (LDS-reduced, then
// one coalesced global atomic per row). Skip blocks bn > bm+1 (fully masked).
__global__ __launch_bounds__(256, 2) void s_gemm(
    const unsigned short* __restrict__ Qr, const unsigned short* __restrict__ Kr,
    unsigned short* __restrict__ Sb, float* __restrict__ rowsums) {
  __shared__ __align__(16) unsigned short As[BM * BK];
  __shared__ __align__(16) unsigned short Bs[BN * BK];
  const int tid = threadIdx.x, lane = tid & 63, wave = tid >> 6;
  const int bm = blockIdx.y, bn = blockIdx.x, z = blockIdx.z;
  if (bn > bm + 1) return;
  const unsigned short* A = Qr + (long)z * 2048 * 1024;
  const unsigned short* B = Kr + (long)z * 2048 * 1024;
  unsigned short* S = Sb + (long)z * 2048 * 2048;
  float* rs = rowsums + (long)z * 2048;
  const int m0 = bm * BM, n0 = bn * BN;
  const int wm = (wave >> 1) * 64, wn = (wave & 1) * 64;
  const int q = lane >> 4, fm = lane & 15;

  f32x4 acc[4][4];
#pragma unroll
  for (int i = 0; i < 4; ++i)
#pragma unroll
    for (int j = 0; j < 4; ++j) acc[i][j] = (f32x4)(0.f);

  gemm_body(A, B, As, Bs, 1024, 1024, m0, n0, 16, tid, lane, wave, acc);

  // rowsum scratch overlays Bs (all frag reads are complete after a barrier)
  float* rsum = (float*)Bs;
  __syncthreads();
  if (tid < 128) rsum[tid] = 0.f;
  __syncthreads();

  // mask + exp + store E + per-row partial sums
#pragma unroll
  for (int i = 0; i < 4; ++i) {
    int gmB = m0 + wm + i * 16 + q * 4;
    float ps[4] = {0.f, 0.f, 0.f, 0.f};
#pragma unroll
    for (int j = 0; j < 4; ++j) {
      int gn = n0 + wn + j * 16 + fm;
#pragma unroll
      for (int r = 0; r < 4; ++r) {
        float e = (gn <= gmB + r + 1) ? __expf(acc[i][j][r] * 0.03125f) : 0.f;
        unsigned short h = f2bf(e);
        S[(long)(gmB + r) * 2048 + gn] = h;
        ps[r] += bf2f(h);  // sum the rounded value (matches stored E)
      }
    }
#pragma unroll
    for (int r = 0; r < 4; ++r) {
      float v = ps[r];
      v += __shfl_xor(v, 1);
      v += __shfl_xor(v, 2);
      v += __shfl_xor(v, 4);
      v += __shfl_xor(v, 8);
      if (fm == 0) atomicAdd(&rsum[wm + i * 16 + q * 4 + r], v);
    }
  }
  __syncthreads();
  if (tid < 128) atomicAdd(&rs[m0 + tid], rsum[tid]);
}

// ---------------------------------------------------------------------------
// out = (E @ Vt^T) / rowsum per batch (z), K-loop truncated causally.
__global__ __launch_bounds__(256, 2) void pv_gemm(
    const unsigned short* __restrict__ Sb, const unsigned short* __restrict__ Vt,
    const float* __restrict__ rowsums, float* __restrict__ out, int b0) {
  __shared__ __align__(16) unsigned short As[BM * BK];
  __shared__ __align__(16) unsigned short Bs[BN * BK];
  const int tid = threadIdx.x, lane = tid & 63, wave = tid >> 6;
  const int bm = blockIdx.y, bn = blockIdx.x, z = blockIdx.z;
  const unsigned short* A = Sb + (long)z * 2048 * 2048;
  const unsigned short* B = Vt + (long)(b0 + z) * 1024 * 2048;
  const float* rs = rowsums + (long)(b0 + z) * 2048;
  float* C = out + (long)(b0 + z) * 2048 * 1024;
  int ktiles = 2 * bm + 3;  // keys valid up to q+1, q <= m0+127; BK=64
  if (ktiles > 32) ktiles = 32;
  const int m0 = bm * BM, n0 = bn * BN;
  const int wm = (wave >> 1) * 64, wn = (wave & 1) * 64;
  const int q = lane >> 4, fm = lane & 15;

  f32x4 acc[4][4];
#pragma unroll
  for (int i = 0; i < 4; ++i)
#pragma unroll
    for (int j = 0; j < 4; ++j) acc[i][j] = (f32x4)(0.f);

  gemm_body(A, B, As, Bs, 2048, 2048, m0, n0, ktiles, tid, lane, wave, acc);

#pragma unroll
  for (int i = 0; i < 4; ++i) {
    int gmB = m0 + wm + i * 16 + q * 4;
#pragma unroll
    for (int r = 0; r < 4; ++r) {
      float inv = 1.f / rs[gmB + r];
#pragma unroll
      for (int j = 0; j < 4; ++j) {
        int gn = n0 + wn + j * 16 + fm;
        C[(long)(gmB + r) * 1024 + gn] = acc[i][j][r] * inv;
      }
    }
  }
}

// ---------------------------------------------------------------------------
extern "C" void kernel_launch(void* const* d_in, const int* in_sizes, int n_in,
                              void* d_out, int out_size, void* d_ws, size_t ws_size,
                              hipStream_t stream) {
  const float* x = (const float*)d_in[0];
  const float* Wq = (const float*)d_in[1];
  const float* Wk = (const float*)d_in[2];
  const float* Wv = (const float*)d_in[3];
  float* out = (float*)d_out;

  // Layout: rowsums[32 KB] | Qr[16 MB] | Kr[16 MB] | Vt[16 MB] | xb[16 MB] |
  // Wb[6 MB]. E (bf16, 8 MB/batch) overlays xb/Wb (dead after qkv_rope_gemm).
  float* rowsums = (float*)d_ws;                      // [4][2048] fp32
  unsigned short* Qr = (unsigned short*)d_ws + 16384; // +32 KB
  unsigned short* Kr = Qr + (long)8192 * 1024;
  unsigned short* Vt = Kr + (long)8192 * 1024;        // [b][c][t]
  unsigned short* xb = Vt + (long)8192 * 1024;
  unsigned short* Wb = xb + (long)8192 * 1024;
  unsigned short* Sb = xb;                            // bf16 E, BCH x 2048 x 2048

  int BCH = 4;
  while (BCH > 1 && (size_t)32768 + (size_t)(48 + 8 * BCH) * 1024 * 1024 > ws_size)
    BCH >>= 1;

  cvt_all<<<11265, 256, 0, stream>>>((const float4*)x, (const float4*)Wq,
                                     (const float4*)Wk, (const float4*)Wv,
                                     (ushort4*)xb, (ushort4*)Wb, (float4*)rowsums);

  qkv_rope_gemm<<<dim3(64, 24), 256, 0, stream>>>(xb, Wb, Qr, Kr, Vt);

  for (int b0 = 0; b0 < 4; b0 += BCH) {
    s_gemm<<<dim3(16, 16, BCH), 256, 0, stream>>>(Qr + (long)b0 * 2048 * 1024,
                                                  Kr + (long)b0 * 2048 * 1024,
                                                  Sb, rowsums + (long)b0 * 2048);
    pv_gemm<<<dim3(8, 16, BCH), 256, 0, stream>>>(Sb, Vt, rowsums, out, b0);
  }
}

// Round 10
// 252.684 us; speedup vs baseline: 2.5896x; 2.5896x over previous
//
#include <hip/hip_runtime.h>

// ---------------------------------------------------------------------------
// RoPE attention: out = softmax(mask(RoPE(xWq^T) @ RoPE(xWk^T)^T / sqrt(d))) @ (xWv^T)
// B=4, T=2048, d=1024. fp32 in/out, bf16 MFMA internally.
// R9 -> R10: staging rebuilt m97-style: global_load_lds (width=16) direct
// HBM->LDS DMA, BK=64, NO staging/prefetch VGPRs (the R8/R9 spill is gone at
// the root). ERRATA: R1-R3's 3 GB WRITE_SIZE was libm sincosf stack traffic,
// NOT global_load_lds (WRITE collapsed exactly when sincosf was removed in R4;
// m97 uses global_load_lds at 874 TF with this tile shape). XOR swizzle folded
// into the GLOBAL chunk mapping (c=(f&7)^((f>>3)&7)) so the DMA's forced
// lane-contiguous LDS layout is still conflict-free for frag reads (R8: 0).
// Plain __launch_bounds__(256) — R9 proved the (256,2) hint backfires.
// ---------------------------------------------------------------------------

typedef float f32x4 __attribute__((ext_vector_type(4)));
typedef __bf16 bf16x8 __attribute__((ext_vector_type(8)));

#define BM 128
#define BN 128
#define BK 64  // ushorts per LDS tile row; 128x64x2B = 16 KB per buffer

__device__ __forceinline__ unsigned short f2bf(float f) {
  union { float f; unsigned int u; } c; c.f = f;
  unsigned int u = c.u;
  u += 0x7fffu + ((u >> 16) & 1u);  // round-nearest-even
  return (unsigned short)(u >> 16);
}
__device__ __forceinline__ float bf2f(unsigned short h) {
  union { unsigned int u; float f; } c; c.u = ((unsigned int)h) << 16;
  return c.f;
}

__device__ __forceinline__ void async16(const unsigned short* gp, unsigned short* lp) {
  __builtin_amdgcn_global_load_lds(
      (const __attribute__((address_space(1))) void*)gp,
      (__attribute__((address_space(3))) void*)lp, 16, 0, 0);
}

// ---------------------------------------------------------------------------
// All fp32->bf16 casts in one kernel; last block zeroes rowsums.
__global__ __launch_bounds__(256) void cvt_all(
    const float4* __restrict__ x, const float4* __restrict__ wq,
    const float4* __restrict__ wk, const float4* __restrict__ wv,
    ushort4* __restrict__ xb, ushort4* __restrict__ wb,
    float4* __restrict__ rowsums) {
  int b = blockIdx.x, t = threadIdx.x;
  if (b == 11264) {  // zero rowsums: 4*2048 fp32 = 2048 float4
#pragma unroll
    for (int i = 0; i < 8; ++i) rowsums[i * 256 + t] = float4{0.f, 0.f, 0.f, 0.f};
    return;
  }
  const float4* src;
  ushort4* dst;
  long i;
  if (b < 8192) { src = x; dst = xb; i = (long)b * 256 + t; }
  else if (b < 9216) { src = wq; dst = wb; i = (long)(b - 8192) * 256 + t; }
  else if (b < 10240) { src = wk; dst = wb + 262144; i = (long)(b - 9216) * 256 + t; }
  else { src = wv; dst = wb + 524288; i = (long)(b - 10240) * 256 + t; }
  float4 v = src[i];
  ushort4 o;
  o.x = f2bf(v.x); o.y = f2bf(v.y); o.z = f2bf(v.z); o.w = f2bf(v.w);
  dst[i] = o;
}

// ---------------------------------------------------------------------------
// NT-GEMM K-loop, BK=64, global_load_lds staging (m97 structure):
// C[m,n] = sum_k A[m,k]*B[n,k]. 128x128 tile, 4 waves (2x2), each 64x64 via
// 4x4 frags of mfma_f32_16x16x32_bf16, two k-steps of 32 per LDS tile.
// LDS position f (16-B units) holds (row=f>>3, granule g=f&7); the staged
// global chunk is c = g ^ (row&7) — XOR swizzle in the gather, so the DMA's
// lane-contiguous LDS write order is also conflict-free for frag reads.
__device__ __forceinline__ void gemm_body(
    const unsigned short* __restrict__ A, const unsigned short* __restrict__ B,
    unsigned short* As, unsigned short* Bs,
    int lda, int ldb, int m0, int n0, int ktiles,
    int tid, int lane, int wave, f32x4 acc[4][4]) {
  const int wm = (wave >> 1) * 64;
  const int wn = (wave & 1) * 64;
  const int fm = lane & 15;
  const int q = lane >> 4;

  // per-lane global offsets for the 4 staging positions of each matrix
  long goffA[4], goffB[4];
#pragma unroll
  for (int p = 0; p < 4; ++p) {
    int f = p * 256 + tid;
    int row = f >> 3;
    int c = (f & 7) ^ (row & 7);
    goffA[p] = (long)(m0 + row) * lda + c * 8;
    goffB[p] = (long)(n0 + row) * ldb + c * 8;
  }

  for (int kt = 0; kt < ktiles; ++kt) {
    const long k0 = (long)kt * BK;
    __syncthreads();  // prior frag reads done before LDS overwrite
#pragma unroll
    for (int p = 0; p < 4; ++p) {
      async16(A + goffA[p] + k0, As + (p * 256 + tid) * 8);
      async16(B + goffB[p] + k0, Bs + (p * 256 + tid) * 8);
    }
    __syncthreads();  // compiler drains vmcnt(0): tiles ready

#pragma unroll
    for (int s = 0; s < 2; ++s) {  // two k-steps of 32
      bf16x8 af[4], bfr[4];
#pragma unroll
      for (int i = 0; i < 4; ++i) {
        int row = wm + i * 16 + fm;
        af[i] = *(const bf16x8*)&As[row * 64 + ((((s << 2) | q) ^ (row & 7)) << 3)];
      }
#pragma unroll
      for (int j = 0; j < 4; ++j) {
        int row = wn + j * 16 + fm;
        bfr[j] = *(const bf16x8*)&Bs[row * 64 + ((((s << 2) | q) ^ (row & 7)) << 3)];
      }
#pragma unroll
      for (int i = 0; i < 4; ++i)
#pragma unroll
        for (int j = 0; j < 4; ++j)
          acc[i][j] = __builtin_amdgcn_mfma_f32_16x16x32_bf16(af[i], bfr[j], acc[i][j], 0, 0, 0);
    }
  }
}

// ---------------------------------------------------------------------------
// QKV projection + RoPE. A=xb[8192x1024], B=Wb[3072x1024]. Grid (bm=64, bn=24).
__global__ __launch_bounds__(256) void qkv_rope_gemm(
    const unsigned short* __restrict__ A, const unsigned short* __restrict__ B,
    unsigned short* __restrict__ Qr, unsigned short* __restrict__ Kr,
    unsigned short* __restrict__ Vt) {
  __shared__ __align__(16) unsigned short As[BM * BK];
  __shared__ __align__(16) unsigned short Bs[BN * BK];
  const int tid = threadIdx.x, lane = tid & 63, wave = tid >> 6;
  const int bm = blockIdx.x, bn = blockIdx.y;
  const int m0 = bm * BM, n0 = bn * BN;
  const int wm = (wave >> 1) * 64, wn = (wave & 1) * 64;
  const int q = lane >> 4, fm = lane & 15;

  f32x4 acc[4][4];
#pragma unroll
  for (int i = 0; i < 4; ++i)
#pragma unroll
    for (int j = 0; j < 4; ++j) acc[i][j] = (f32x4)(0.f);

  gemm_body(A, B, As, Bs, 1024, 1024, m0, n0, 16, tid, lane, wave, acc);

  if (n0 < 2048) {
    // Q or K: RoPE (pair (2c,2c+1) in adjacent lanes), chained angle addition:
    // 6 sincos per j; per-element rotation by precomputed delta (r:+1, i:+16).
    const float NEG = -13.287712379549449f / 1024.f;  // -log2(1e4)/1024
    unsigned short* dst = (n0 < 1024) ? Qr : Kr;
    const int t00 = (m0 + wm + q * 4) & 2047;
#pragma unroll
    for (int j = 0; j < 4; ++j) {
      int c = (n0 & 1023) + wn + j * 16 + fm;
      float th = exp2f((float)(c & ~1) * NEG);
      float sgn = (c & 1) ? 1.f : -1.f;
      float ang0 = (float)t00 * th;
      float cb = __cosf(ang0), sb = __sinf(ang0);
      float c1 = __cosf(th), s1 = __sinf(th);
      float c16 = __cosf(16.f * th), s16 = __sinf(16.f * th);
#pragma unroll
      for (int i = 0; i < 4; ++i) {
        int gmB = m0 + wm + i * 16 + q * 4;
        float cr = cb, sr = sb;
#pragma unroll
        for (int r = 0; r < 4; ++r) {
          float v = acc[i][j][r];
          float p = __shfl_xor(v, 1);
          dst[(long)(gmB + r) * 1024 + c] = f2bf(v * cr + sgn * p * sr);
          float crn = cr * c1 - sr * s1;
          sr = sr * c1 + cr * s1;
          cr = crn;
        }
        float cbn = cb * c16 - sb * s16;
        sb = sb * c16 + cb * s16;
        cb = cbn;
      }
    }
  } else {
    // V: transpose to Vt[b][c][t]; 4 consecutive t per lane -> 8-B stores
    const int c0 = n0 - 2048;
#pragma unroll
    for (int j = 0; j < 4; ++j) {
      int c = c0 + wn + j * 16 + fm;
#pragma unroll
      for (int i = 0; i < 4; ++i) {
        int gmB = m0 + wm + i * 16 + q * 4;
        int b = gmB >> 11, t = gmB & 2047;
        ushort4 pk;
        pk.x = f2bf(acc[i][j][0]);
        pk.y = f2bf(acc[i][j][1]);
        pk.z = f2bf(acc[i][j][2]);
        pk.w = f2bf(acc[i][j][3]);
        *(ushort4*)&Vt[((long)b * 1024 + c) * 2048 + t] = pk;
      }
    }
  }
}

// ---------------------------------------------------------------------------
// E = exp(mask(Qr@Kr^T)/32) per batch (z), bf16, + rowsums (LDS-reduced, then
// one coalesced global atomic per row). Skip blocks bn > bm+1 (fully masked).
__global__ __launch_bounds__(256) void s_gemm(
    const unsigned short* __restrict__ Qr, const unsigned short* __restrict__ Kr,
    unsigned short* __restrict__ Sb, float* __restrict__ rowsums) {
  __shared__ __align__(16) unsigned short As[BM * BK];
  __shared__ __align__(16) unsigned short Bs[BN * BK];
  const int tid = threadIdx.x, lane = tid & 63, wave = tid >> 6;
  const int bm = blockIdx.y, bn = blockIdx.x, z = blockIdx.z;
  if (bn > bm + 1) return;
  const unsigned short* A = Qr + (long)z * 2048 * 1024;
  const unsigned short* B = Kr + (long)z * 2048 * 1024;
  unsigned short* S = Sb + (long)z * 2048 * 2048;
  float* rs = rowsums + (long)z * 2048;
  const int m0 = bm * BM, n0 = bn * BN;
  const int wm = (wave >> 1) * 64, wn = (wave & 1) * 64;
  const int q = lane >> 4, fm = lane & 15;

  f32x4 acc[4][4];
#pragma unroll
  for (int i = 0; i < 4; ++i)
#pragma unroll
    for (int j = 0; j < 4; ++j) acc[i][j] = (f32x4)(0.f);

  gemm_body(A, B, As, Bs, 1024, 1024, m0, n0, 16, tid, lane, wave, acc);

  // rowsum scratch overlays Bs (all frag reads are complete after a barrier)
  float* rsum = (float*)Bs;
  __syncthreads();
  if (tid < 128) rsum[tid] = 0.f;
  __syncthreads();

  // mask + exp + store E + per-row partial sums
#pragma unroll
  for (int i = 0; i < 4; ++i) {
    int gmB = m0 + wm + i * 16 + q * 4;
    float ps[4] = {0.f, 0.f, 0.f, 0.f};
#pragma unroll
    for (int j = 0; j < 4; ++j) {
      int gn = n0 + wn + j * 16 + fm;
#pragma unroll
      for (int r = 0; r < 4; ++r) {
        float e = (gn <= gmB + r + 1) ? __expf(acc[i][j][r] * 0.03125f) : 0.f;
        unsigned short h = f2bf(e);
        S[(long)(gmB + r) * 2048 + gn] = h;
        ps[r] += bf2f(h);  // sum the rounded value (matches stored E)
      }
    }
#pragma unroll
    for (int r = 0; r < 4; ++r) {
      float v = ps[r];
      v += __shfl_xor(v, 1);
      v += __shfl_xor(v, 2);
      v += __shfl_xor(v, 4);
      v += __shfl_xor(v, 8);
      if (fm == 0) atomicAdd(&rsum[wm + i * 16 + q * 4 + r], v);
    }
  }
  __syncthreads();
  if (tid < 128) atomicAdd(&rs[m0 + tid], rsum[tid]);
}

// ---------------------------------------------------------------------------
// out = (E @ Vt^T) / rowsum per batch (z), K-loop truncated causally.
__global__ __launch_bounds__(256) void pv_gemm(
    const unsigned short* __restrict__ Sb, const unsigned short* __restrict__ Vt,
    const float* __restrict__ rowsums, float* __restrict__ out, int b0) {
  __shared__ __align__(16) unsigned short As[BM * BK];
  __shared__ __align__(16) unsigned short Bs[BN * BK];
  const int tid = threadIdx.x, lane = tid & 63, wave = tid >> 6;
  const int bm = blockIdx.y, bn = blockIdx.x, z = blockIdx.z;
  const unsigned short* A = Sb + (long)z * 2048 * 2048;
  const unsigned short* B = Vt + (long)(b0 + z) * 1024 * 2048;
  const float* rs = rowsums + (long)(b0 + z) * 2048;
  float* C = out + (long)(b0 + z) * 2048 * 1024;
  int ktiles = 2 * bm + 3;  // keys valid up to q+1, q <= m0+127; BK=64
  if (ktiles > 32) ktiles = 32;
  const int m0 = bm * BM, n0 = bn * BN;
  const int wm = (wave >> 1) * 64, wn = (wave & 1) * 64;
  const int q = lane >> 4, fm = lane & 15;

  f32x4 acc[4][4];
#pragma unroll
  for (int i = 0; i < 4; ++i)
#pragma unroll
    for (int j = 0; j < 4; ++j) acc[i][j] = (f32x4)(0.f);

  gemm_body(A, B, As, Bs, 2048, 2048, m0, n0, ktiles, tid, lane, wave, acc);

#pragma unroll
  for (int i = 0; i < 4; ++i) {
    int gmB = m0 + wm + i * 16 + q * 4;
#pragma unroll
    for (int r = 0; r < 4; ++r) {
      float inv = 1.f / rs[gmB + r];
#pragma unroll
      for (int j = 0; j < 4; ++j) {
        int gn = n0 + wn + j * 16 + fm;
        C[(long)(gmB + r) * 1024 + gn] = acc[i][j][r] * inv;
      }
    }
  }
}

// ---------------------------------------------------------------------------
extern "C" void kernel_launch(void* const* d_in, const int* in_sizes, int n_in,
                              void* d_out, int out_size, void* d_ws, size_t ws_size,
                              hipStream_t stream) {
  const float* x = (const float*)d_in[0];
  const float* Wq = (const float*)d_in[1];
  const float* Wk = (const float*)d_in[2];
  const float* Wv = (const float*)d_in[3];
  float* out = (float*)d_out;

  // Layout: rowsums[32 KB] | Qr[16 MB] | Kr[16 MB] | Vt[16 MB] | xb[16 MB] |
  // Wb[6 MB]. E (bf16, 8 MB/batch) overlays xb/Wb (dead after qkv_rope_gemm).
  float* rowsums = (float*)d_ws;                      // [4][2048] fp32
  unsigned short* Qr = (unsigned short*)d_ws + 16384; // +32 KB
  unsigned short* Kr = Qr + (long)8192 * 1024;
  unsigned short* Vt = Kr + (long)8192 * 1024;        // [b][c][t]
  unsigned short* xb = Vt + (long)8192 * 1024;
  unsigned short* Wb = xb + (long)8192 * 1024;
  unsigned short* Sb = xb;                            // bf16 E, BCH x 2048 x 2048

  int BCH = 4;
  while (BCH > 1 && (size_t)32768 + (size_t)(48 + 8 * BCH) * 1024 * 1024 > ws_size)
    BCH >>= 1;

  cvt_all<<<11265, 256, 0, stream>>>((const float4*)x, (const float4*)Wq,
                                     (const float4*)Wk, (const float4*)Wv,
                                     (ushort4*)xb, (ushort4*)Wb, (float4*)rowsums);

  qkv_rope_gemm<<<dim3(64, 24), 256, 0, stream>>>(xb, Wb, Qr, Kr, Vt);

  for (int b0 = 0; b0 < 4; b0 += BCH) {
    s_gemm<<<dim3(16, 16, BCH), 256, 0, stream>>>(Qr + (long)b0 * 2048 * 1024,
                                                  Kr + (long)b0 * 2048 * 1024,
                                                  Sb, rowsums + (long)b0 * 2048);
    pv_gemm<<<dim3(8, 16, BCH), 256, 0, stream>>>(Sb, Vt, rowsums, out, b0);
  }
}

// Round 11
// 249.143 us; speedup vs baseline: 2.6264x; 1.0142x over previous
//
#include <hip/hip_runtime.h>

// ---------------------------------------------------------------------------
// RoPE attention: out = softmax(mask(RoPE(xWq^T) @ RoPE(xWk^T)^T / sqrt(d))) @ (xWv^T)
// B=4, T=2048, d=1024. fp32 in/out, bf16 MFMA internally.
// R10 -> R11: AITER-style pipelined K-loop. Double-buffered LDS (2x32 KB) with
// global_load_lds DMA + raw s_barrier + s_waitcnt vmcnt(8) (never 0): tile
// kt+1's DMAs stay in flight across tile kt's 32 MFMAs, removing the per-iter
// vmcnt(0) barrier drain (R10: MfmaUtil 26%, VALU 39%, ~2 blocks/CU -> drain
// poorly hidden). Tail fixes: s_gemm compact triangular grid (151 blocks/batch,
// no no-op dispatches); pv_gemm bm descending (32-ktile diagonal blocks first).
// ---------------------------------------------------------------------------

typedef float f32x4 __attribute__((ext_vector_type(4)));
typedef __bf16 bf16x8 __attribute__((ext_vector_type(8)));

#define BM 128
#define BN 128
#define BK 64       // ushorts per LDS tile row
#define TILE (BM * BK)  // 8192 ushorts = 16 KB per buffer per matrix

__device__ __forceinline__ unsigned short f2bf(float f) {
  union { float f; unsigned int u; } c; c.f = f;
  unsigned int u = c.u;
  u += 0x7fffu + ((u >> 16) & 1u);  // round-nearest-even
  return (unsigned short)(u >> 16);
}
__device__ __forceinline__ float bf2f(unsigned short h) {
  union { unsigned int u; float f; } c; c.u = ((unsigned int)h) << 16;
  return c.f;
}

__device__ __forceinline__ void async16(const unsigned short* gp, unsigned short* lp) {
  __builtin_amdgcn_global_load_lds(
      (const __attribute__((address_space(1))) void*)gp,
      (__attribute__((address_space(3))) void*)lp, 16, 0, 0);
}

// ---------------------------------------------------------------------------
// All fp32->bf16 casts in one kernel; last block zeroes rowsums.
__global__ __launch_bounds__(256) void cvt_all(
    const float4* __restrict__ x, const float4* __restrict__ wq,
    const float4* __restrict__ wk, const float4* __restrict__ wv,
    ushort4* __restrict__ xb, ushort4* __restrict__ wb,
    float4* __restrict__ rowsums) {
  int b = blockIdx.x, t = threadIdx.x;
  if (b == 11264) {  // zero rowsums: 4*2048 fp32 = 2048 float4
#pragma unroll
    for (int i = 0; i < 8; ++i) rowsums[i * 256 + t] = float4{0.f, 0.f, 0.f, 0.f};
    return;
  }
  const float4* src;
  ushort4* dst;
  long i;
  if (b < 8192) { src = x; dst = xb; i = (long)b * 256 + t; }
  else if (b < 9216) { src = wq; dst = wb; i = (long)(b - 8192) * 256 + t; }
  else if (b < 10240) { src = wk; dst = wb + 262144; i = (long)(b - 9216) * 256 + t; }
  else { src = wv; dst = wb + 524288; i = (long)(b - 10240) * 256 + t; }
  float4 v = src[i];
  ushort4 o;
  o.x = f2bf(v.x); o.y = f2bf(v.y); o.z = f2bf(v.z); o.w = f2bf(v.w);
  dst[i] = o;
}

// ---------------------------------------------------------------------------
// Pipelined NT-GEMM K-loop, BK=64, double-buffered global_load_lds DMA.
// C[m,n] = sum_k A[m,k]*B[n,k]. 128x128 tile, 4 waves (2x2), each 64x64 via
// 4x4 frags of mfma_f32_16x16x32_bf16, two k-steps of 32 per LDS tile.
// LDS position f (16-B units) holds (row=f>>3, granule g=f&7); staged global
// chunk c = g ^ (row&7) — XOR swizzle in the gather keeps the DMA's
// lane-contiguous LDS layout conflict-free for frag reads (R10: 0 conflicts).
// Pipeline per iter: barrier A (prev readers of other buf done) -> issue 8
// DMAs for tile kt+1 into other buf -> vmcnt(8) (tile kt's 8 oldest done,
// kt+1's stay in flight) -> barrier B -> 32 MFMAs from current buf.
__device__ __forceinline__ void gemm_body(
    const unsigned short* __restrict__ A, const unsigned short* __restrict__ B,
    unsigned short* As, unsigned short* Bs,  // each 2*TILE ushorts
    int lda, int ldb, int m0, int n0, int ktiles,
    int tid, int lane, int wave, f32x4 acc[4][4]) {
  const int wm = (wave >> 1) * 64;
  const int wn = (wave & 1) * 64;
  const int fm = lane & 15;
  const int q = lane >> 4;

  long goffA[4], goffB[4];
#pragma unroll
  for (int p = 0; p < 4; ++p) {
    int f = p * 256 + tid;
    int row = f >> 3;
    int c = (f & 7) ^ (row & 7);
    goffA[p] = (long)(m0 + row) * lda + c * 8;
    goffB[p] = (long)(n0 + row) * ldb + c * 8;
  }

  // prologue: tile 0 -> buffer 0 (8 DMAs in flight)
#pragma unroll
  for (int p = 0; p < 4; ++p) {
    async16(A + goffA[p], As + (p * 256 + tid) * 8);
    async16(B + goffB[p], Bs + (p * 256 + tid) * 8);
  }

  for (int kt = 0; kt < ktiles; ++kt) {
    const int cur = (kt & 1) * TILE;
    const int nxt = ((kt + 1) & 1) * TILE;

    asm volatile("s_barrier" ::: "memory");  // (A) prev readers of buf[nxt] done
    if (kt + 1 < ktiles) {
      const long k0 = (long)(kt + 1) * BK;
#pragma unroll
      for (int p = 0; p < 4; ++p) {
        async16(A + goffA[p] + k0, As + nxt + (p * 256 + tid) * 8);
        async16(B + goffB[p] + k0, Bs + nxt + (p * 256 + tid) * 8);
      }
      asm volatile("s_waitcnt vmcnt(8)" ::: "memory");  // tile kt done; kt+1 in flight
    } else {
      asm volatile("s_waitcnt vmcnt(0)" ::: "memory");  // last tile: drain all
    }
    asm volatile("s_barrier" ::: "memory");  // (B) everyone's tile-kt DMAs done

#pragma unroll
    for (int s = 0; s < 2; ++s) {  // two k-steps of 32
      bf16x8 af[4], bfr[4];
#pragma unroll
      for (int i = 0; i < 4; ++i) {
        int row = wm + i * 16 + fm;
        af[i] = *(const bf16x8*)&As[cur + row * 64 + ((((s << 2) | q) ^ (row & 7)) << 3)];
      }
#pragma unroll
      for (int j = 0; j < 4; ++j) {
        int row = wn + j * 16 + fm;
        bfr[j] = *(const bf16x8*)&Bs[cur + row * 64 + ((((s << 2) | q) ^ (row & 7)) << 3)];
      }
#pragma unroll
      for (int i = 0; i < 4; ++i)
#pragma unroll
        for (int j = 0; j < 4; ++j)
          acc[i][j] = __builtin_amdgcn_mfma_f32_16x16x32_bf16(af[i], bfr[j], acc[i][j], 0, 0, 0);
    }
  }
}

// ---------------------------------------------------------------------------
// QKV projection + RoPE. A=xb[8192x1024], B=Wb[3072x1024]. Grid (bm=64, bn=24).
__global__ __launch_bounds__(256) void qkv_rope_gemm(
    const unsigned short* __restrict__ A, const unsigned short* __restrict__ B,
    unsigned short* __restrict__ Qr, unsigned short* __restrict__ Kr,
    unsigned short* __restrict__ Vt) {
  __shared__ __align__(16) unsigned short As[2 * TILE];
  __shared__ __align__(16) unsigned short Bs[2 * TILE];
  const int tid = threadIdx.x, lane = tid & 63, wave = tid >> 6;
  const int bm = blockIdx.x, bn = blockIdx.y;
  const int m0 = bm * BM, n0 = bn * BN;
  const int wm = (wave >> 1) * 64, wn = (wave & 1) * 64;
  const int q = lane >> 4, fm = lane & 15;

  f32x4 acc[4][4];
#pragma unroll
  for (int i = 0; i < 4; ++i)
#pragma unroll
    for (int j = 0; j < 4; ++j) acc[i][j] = (f32x4)(0.f);

  gemm_body(A, B, As, Bs, 1024, 1024, m0, n0, 16, tid, lane, wave, acc);

  if (n0 < 2048) {
    // Q or K: RoPE (pair (2c,2c+1) in adjacent lanes), chained angle addition.
    const float NEG = -13.287712379549449f / 1024.f;  // -log2(1e4)/1024
    unsigned short* dst = (n0 < 1024) ? Qr : Kr;
    const int t00 = (m0 + wm + q * 4) & 2047;
#pragma unroll
    for (int j = 0; j < 4; ++j) {
      int c = (n0 & 1023) + wn + j * 16 + fm;
      float th = exp2f((float)(c & ~1) * NEG);
      float sgn = (c & 1) ? 1.f : -1.f;
      float ang0 = (float)t00 * th;
      float cb = __cosf(ang0), sb = __sinf(ang0);
      float c1 = __cosf(th), s1 = __sinf(th);
      float c16 = __cosf(16.f * th), s16 = __sinf(16.f * th);
#pragma unroll
      for (int i = 0; i < 4; ++i) {
        int gmB = m0 + wm + i * 16 + q * 4;
        float cr = cb, sr = sb;
#pragma unroll
        for (int r = 0; r < 4; ++r) {
          float v = acc[i][j][r];
          float p = __shfl_xor(v, 1);
          dst[(long)(gmB + r) * 1024 + c] = f2bf(v * cr + sgn * p * sr);
          float crn = cr * c1 - sr * s1;
          sr = sr * c1 + cr * s1;
          cr = crn;
        }
        float cbn = cb * c16 - sb * s16;
        sb = sb * c16 + cb * s16;
        cb = cbn;
      }
    }
  } else {
    // V: transpose to Vt[b][c][t]; 4 consecutive t per lane -> 8-B stores
    const int c0 = n0 - 2048;
#pragma unroll
    for (int j = 0; j < 4; ++j) {
      int c = c0 + wn + j * 16 + fm;
#pragma unroll
      for (int i = 0; i < 4; ++i) {
        int gmB = m0 + wm + i * 16 + q * 4;
        int b = gmB >> 11, t = gmB & 2047;
        ushort4 pk;
        pk.x = f2bf(acc[i][j][0]);
        pk.y = f2bf(acc[i][j][1]);
        pk.z = f2bf(acc[i][j][2]);
        pk.w = f2bf(acc[i][j][3]);
        *(ushort4*)&Vt[((long)b * 1024 + c) * 2048 + t] = pk;
      }
    }
  }
}

// ---------------------------------------------------------------------------
// E = exp(mask(Qr@Kr^T)/32) per batch (z), bf16, + rowsums. Compact triangular
// grid: 151 blocks/batch, decode (bm,bn) from linear idx (no no-op blocks).
__global__ __launch_bounds__(256) void s_gemm(
    const unsigned short* __restrict__ Qr, const unsigned short* __restrict__ Kr,
    unsigned short* __restrict__ Sb, float* __restrict__ rowsums) {
  __shared__ __align__(16) unsigned short As[2 * TILE];
  __shared__ __align__(16) unsigned short Bs[2 * TILE];
  const int tid = threadIdx.x, lane = tid & 63, wave = tid >> 6;
  const int z = blockIdx.z;
  int idx = blockIdx.x, bm = 0;
#pragma unroll 1
  for (; bm < 16; ++bm) {  // counts per bm: min(bm+2,16); total 151
    int cnt = (bm + 2 > 16) ? 16 : bm + 2;
    if (idx < cnt) break;
    idx -= cnt;
  }
  const int bn = idx;
  const unsigned short* A = Qr + (long)z * 2048 * 1024;
  const unsigned short* B = Kr + (long)z * 2048 * 1024;
  unsigned short* S = Sb + (long)z * 2048 * 2048;
  float* rs = rowsums + (long)z * 2048;
  const int m0 = bm * BM, n0 = bn * BN;
  const int wm = (wave >> 1) * 64, wn = (wave & 1) * 64;
  const int q = lane >> 4, fm = lane & 15;

  f32x4 acc[4][4];
#pragma unroll
  for (int i = 0; i < 4; ++i)
#pragma unroll
    for (int j = 0; j < 4; ++j) acc[i][j] = (f32x4)(0.f);

  gemm_body(A, B, As, Bs, 1024, 1024, m0, n0, 16, tid, lane, wave, acc);

  // rowsum scratch overlays Bs (frag reads complete; DMAs drained by vmcnt(0))
  float* rsum = (float*)Bs;
  __syncthreads();
  if (tid < 128) rsum[tid] = 0.f;
  __syncthreads();

#pragma unroll
  for (int i = 0; i < 4; ++i) {
    int gmB = m0 + wm + i * 16 + q * 4;
    float ps[4] = {0.f, 0.f, 0.f, 0.f};
#pragma unroll
    for (int j = 0; j < 4; ++j) {
      int gn = n0 + wn + j * 16 + fm;
#pragma unroll
      for (int r = 0; r < 4; ++r) {
        float e = (gn <= gmB + r + 1) ? __expf(acc[i][j][r] * 0.03125f) : 0.f;
        unsigned short h = f2bf(e);
        S[(long)(gmB + r) * 2048 + gn] = h;
        ps[r] += bf2f(h);  // sum the rounded value (matches stored E)
      }
    }
#pragma unroll
    for (int r = 0; r < 4; ++r) {
      float v = ps[r];
      v += __shfl_xor(v, 1);
      v += __shfl_xor(v, 2);
      v += __shfl_xor(v, 4);
      v += __shfl_xor(v, 8);
      if (fm == 0) atomicAdd(&rsum[wm + i * 16 + q * 4 + r], v);
    }
  }
  __syncthreads();
  if (tid < 128) atomicAdd(&rs[m0 + tid], rsum[tid]);
}

// ---------------------------------------------------------------------------
// out = (E @ Vt^T) / rowsum per batch (z), K-loop truncated causally.
// bm descending: longest-K blocks (diagonal) dispatch first (tail balance).
__global__ __launch_bounds__(256) void pv_gemm(
    const unsigned short* __restrict__ Sb, const unsigned short* __restrict__ Vt,
    const float* __restrict__ rowsums, float* __restrict__ out, int b0) {
  __shared__ __align__(16) unsigned short As[2 * TILE];
  __shared__ __align__(16) unsigned short Bs[2 * TILE];
  const int tid = threadIdx.x, lane = tid & 63, wave = tid >> 6;
  const int bm = 15 - blockIdx.y, bn = blockIdx.x, z = blockIdx.z;
  const unsigned short* A = Sb + (long)z * 2048 * 2048;
  const unsigned short* B = Vt + (long)(b0 + z) * 1024 * 2048;
  const float* rs = rowsums + (long)(b0 + z) * 2048;
  float* C = out + (long)(b0 + z) * 2048 * 1024;
  int ktiles = 2 * bm + 3;  // keys valid up to q+1, q <= m0+127; BK=64
  if (ktiles > 32) ktiles = 32;
  const int m0 = bm * BM, n0 = bn * BN;
  const int wm = (wave >> 1) * 64, wn = (wave & 1) * 64;
  const int q = lane >> 4, fm = lane & 15;

  f32x4 acc[4][4];
#pragma unroll
  for (int i = 0; i < 4; ++i)
#pragma unroll
    for (int j = 0; j < 4; ++j) acc[i][j] = (f32x4)(0.f);

  gemm_body(A, B, As, Bs, 2048, 2048, m0, n0, ktiles, tid, lane, wave, acc);

#pragma unroll
  for (int i = 0; i < 4; ++i) {
    int gmB = m0 + wm + i * 16 + q * 4;
#pragma unroll
    for (int r = 0; r < 4; ++r) {
      float inv = 1.f / rs[gmB + r];
#pragma unroll
      for (int j = 0; j < 4; ++j) {
        int gn = n0 + wn + j * 16 + fm;
        C[(long)(gmB + r) * 1024 + gn] = acc[i][j][r] * inv;
      }
    }
  }
}

// ---------------------------------------------------------------------------
extern "C" void kernel_launch(void* const* d_in, const int* in_sizes, int n_in,
                              void* d_out, int out_size, void* d_ws, size_t ws_size,
                              hipStream_t stream) {
  const float* x = (const float*)d_in[0];
  const float* Wq = (const float*)d_in[1];
  const float* Wk = (const float*)d_in[2];
  const float* Wv = (const float*)d_in[3];
  float* out = (float*)d_out;

  // Layout: rowsums[32 KB] | Qr[16 MB] | Kr[16 MB] | Vt[16 MB] | xb[16 MB] |
  // Wb[6 MB]. E (bf16, 8 MB/batch) overlays xb/Wb (dead after qkv_rope_gemm).
  float* rowsums = (float*)d_ws;                      // [4][2048] fp32
  unsigned short* Qr = (unsigned short*)d_ws + 16384; // +32 KB
  unsigned short* Kr = Qr + (long)8192 * 1024;
  unsigned short* Vt = Kr + (long)8192 * 1024;        // [b][c][t]
  unsigned short* xb = Vt + (long)8192 * 1024;
  unsigned short* Wb = xb + (long)8192 * 1024;
  unsigned short* Sb = xb;                            // bf16 E, BCH x 2048 x 2048

  int BCH = 4;
  while (BCH > 1 && (size_t)32768 + (size_t)(48 + 8 * BCH) * 1024 * 1024 > ws_size)
    BCH >>= 1;

  cvt_all<<<11265, 256, 0, stream>>>((const float4*)x, (const float4*)Wq,
                                     (const float4*)Wk, (const float4*)Wv,
                                     (ushort4*)xb, (ushort4*)Wb, (float4*)rowsums);

  qkv_rope_gemm<<<dim3(64, 24), 256, 0, stream>>>(xb, Wb, Qr, Kr, Vt);

  for (int b0 = 0; b0 < 4; b0 += BCH) {
    s_gemm<<<dim3(151, 1, BCH), 256, 0, stream>>>(Qr + (long)b0 * 2048 * 1024,
                                                  Kr + (long)b0 * 2048 * 1024,
                                                  Sb, rowsums + (long)b0 * 2048);
    pv_gemm<<<dim3(8, 16, BCH), 256, 0, stream>>>(Sb, Vt, rowsums, out, b0);
  }
}

// Round 12
// 226.778 us; speedup vs baseline: 2.8854x; 1.0986x over previous
//
#include <hip/hip_runtime.h>

// ---------------------------------------------------------------------------
// RoPE attention: out = softmax(mask(RoPE(xWq^T) @ RoPE(xWk^T)^T / sqrt(d))) @ (xWv^T)
// B=4, T=2048, d=1024. fp32 in/out, bf16 MFMA internally.
// R11 -> R12: occupancy push 2 -> 3 blocks/CU. R11 proved the barrier drain is
// NOT the cost (dbuf+vmcnt(8) was time-identical to single-buffer); MfmaUtil
// tracks resident blocks (26% @ 2/CU vs m97 37% @ 3/CU). Changes:
//  (1) single-buffer body (dbuf deleted - zero value, frees 32 KB LDS);
//  (2) goff arrays deleted: (p*32)%8==0 makes the XOR chunk p-invariant, so
//      2 base pointers + uniform per-iter adds replace 16 VGPRs;
//  (3) __launch_bounds__(256,3) caps regs at 512/3=170 incl AGPR (est need
//      ~96 VGPR + 64 AGPR = 160). Spill tell for post-mortem: WRITE_SIZE.
// ---------------------------------------------------------------------------

typedef float f32x4 __attribute__((ext_vector_type(4)));
typedef __bf16 bf16x8 __attribute__((ext_vector_type(8)));

#define BM 128
#define BN 128
#define BK 64  // ushorts per LDS tile row; 128x64x2B = 16 KB per buffer

__device__ __forceinline__ unsigned short f2bf(float f) {
  union { float f; unsigned int u; } c; c.f = f;
  unsigned int u = c.u;
  u += 0x7fffu + ((u >> 16) & 1u);  // round-nearest-even
  return (unsigned short)(u >> 16);
}
__device__ __forceinline__ float bf2f(unsigned short h) {
  union { unsigned int u; float f; } c; c.u = ((unsigned int)h) << 16;
  return c.f;
}

__device__ __forceinline__ void async16(const unsigned short* gp, unsigned short* lp) {
  __builtin_amdgcn_global_load_lds(
      (const __attribute__((address_space(1))) void*)gp,
      (__attribute__((address_space(3))) void*)lp, 16, 0, 0);
}

// ---------------------------------------------------------------------------
// All fp32->bf16 casts in one kernel; last block zeroes rowsums.
__global__ __launch_bounds__(256) void cvt_all(
    const float4* __restrict__ x, const float4* __restrict__ wq,
    const float4* __restrict__ wk, const float4* __restrict__ wv,
    ushort4* __restrict__ xb, ushort4* __restrict__ wb,
    float4* __restrict__ rowsums) {
  int b = blockIdx.x, t = threadIdx.x;
  if (b == 11264) {  // zero rowsums: 4*2048 fp32 = 2048 float4
#pragma unroll
    for (int i = 0; i < 8; ++i) rowsums[i * 256 + t] = float4{0.f, 0.f, 0.f, 0.f};
    return;
  }
  const float4* src;
  ushort4* dst;
  long i;
  if (b < 8192) { src = x; dst = xb; i = (long)b * 256 + t; }
  else if (b < 9216) { src = wq; dst = wb; i = (long)(b - 8192) * 256 + t; }
  else if (b < 10240) { src = wk; dst = wb + 262144; i = (long)(b - 9216) * 256 + t; }
  else { src = wv; dst = wb + 524288; i = (long)(b - 10240) * 256 + t; }
  float4 v = src[i];
  ushort4 o;
  o.x = f2bf(v.x); o.y = f2bf(v.y); o.z = f2bf(v.z); o.w = f2bf(v.w);
  dst[i] = o;
}

// ---------------------------------------------------------------------------
// NT-GEMM K-loop, BK=64, single-buffer global_load_lds staging.
// C[m,n] = sum_k A[m,k]*B[n,k]. 128x128 tile, 4 waves (2x2), each 64x64 via
// 4x4 frags of mfma_f32_16x16x32_bf16, two k-steps of 32 per LDS tile.
// LDS position f=p*256+tid (16-B units) holds row=f>>3=p*32+srow; staged
// chunk c = (tid&7)^(srow&7) is p-invariant ((p*32)%8==0) -> two base
// pointers suffice, no per-p offset arrays. XOR swizzle keeps the DMA's
// lane-contiguous LDS layout conflict-free for frag reads (measured 0).
__device__ __forceinline__ void gemm_body(
    const unsigned short* __restrict__ A, const unsigned short* __restrict__ B,
    unsigned short* As, unsigned short* Bs,
    int lda, int ldb, int m0, int n0, int ktiles,
    int tid, int lane, int wave, f32x4 acc[4][4]) {
  const int wm = (wave >> 1) * 64;
  const int wn = (wave & 1) * 64;
  const int fm = lane & 15;
  const int q = lane >> 4;
  const int srow = tid >> 3;                 // 0..31
  const int c = (tid & 7) ^ (srow & 7);      // staged 16-B chunk (p-invariant)
  const unsigned short* Ab = A + (long)(m0 + srow) * lda + c * 8;
  const unsigned short* Bb = B + (long)(n0 + srow) * ldb + c * 8;
  unsigned short* ldA = As + tid * 8;
  unsigned short* ldB = Bs + tid * 8;

  for (int kt = 0; kt < ktiles; ++kt) {
    const long k0 = (long)kt * BK;
    __syncthreads();  // prior frag reads done before LDS overwrite
#pragma unroll
    for (int p = 0; p < 4; ++p) {
      async16(Ab + (long)(p * 32) * lda + k0, ldA + p * 2048);
      async16(Bb + (long)(p * 32) * ldb + k0, ldB + p * 2048);
    }
    __syncthreads();  // compiler drains vmcnt(0): tiles ready

#pragma unroll
    for (int s = 0; s < 2; ++s) {  // two k-steps of 32
      bf16x8 af[4], bfr[4];
#pragma unroll
      for (int i = 0; i < 4; ++i) {
        int row = wm + i * 16 + fm;
        af[i] = *(const bf16x8*)&As[row * 64 + ((((s << 2) | q) ^ (row & 7)) << 3)];
      }
#pragma unroll
      for (int j = 0; j < 4; ++j) {
        int row = wn + j * 16 + fm;
        bfr[j] = *(const bf16x8*)&Bs[row * 64 + ((((s << 2) | q) ^ (row & 7)) << 3)];
      }
#pragma unroll
      for (int i = 0; i < 4; ++i)
#pragma unroll
        for (int j = 0; j < 4; ++j)
          acc[i][j] = __builtin_amdgcn_mfma_f32_16x16x32_bf16(af[i], bfr[j], acc[i][j], 0, 0, 0);
    }
  }
}

// ---------------------------------------------------------------------------
// QKV projection + RoPE. A=xb[8192x1024], B=Wb[3072x1024]. Grid (bm=64, bn=24).
__global__ __launch_bounds__(256, 3) void qkv_rope_gemm(
    const unsigned short* __restrict__ A, const unsigned short* __restrict__ B,
    unsigned short* __restrict__ Qr, unsigned short* __restrict__ Kr,
    unsigned short* __restrict__ Vt) {
  __shared__ __align__(16) unsigned short As[BM * BK];
  __shared__ __align__(16) unsigned short Bs[BN * BK];
  const int tid = threadIdx.x, lane = tid & 63, wave = tid >> 6;
  const int bm = blockIdx.x, bn = blockIdx.y;
  const int m0 = bm * BM, n0 = bn * BN;
  const int wm = (wave >> 1) * 64, wn = (wave & 1) * 64;
  const int q = lane >> 4, fm = lane & 15;

  f32x4 acc[4][4];
#pragma unroll
  for (int i = 0; i < 4; ++i)
#pragma unroll
    for (int j = 0; j < 4; ++j) acc[i][j] = (f32x4)(0.f);

  gemm_body(A, B, As, Bs, 1024, 1024, m0, n0, 16, tid, lane, wave, acc);

  if (n0 < 2048) {
    // Q or K: RoPE (pair (2c,2c+1) in adjacent lanes), chained angle addition.
    const float NEG = -13.287712379549449f / 1024.f;  // -log2(1e4)/1024
    unsigned short* dst = (n0 < 1024) ? Qr : Kr;
    const int t00 = (m0 + wm + q * 4) & 2047;
#pragma unroll
    for (int j = 0; j < 4; ++j) {
      int c = (n0 & 1023) + wn + j * 16 + fm;
      float th = exp2f((float)(c & ~1) * NEG);
      float sgn = (c & 1) ? 1.f : -1.f;
      float ang0 = (float)t00 * th;
      float cb = __cosf(ang0), sb = __sinf(ang0);
      float c1 = __cosf(th), s1 = __sinf(th);
      float c16 = __cosf(16.f * th), s16 = __sinf(16.f * th);
#pragma unroll
      for (int i = 0; i < 4; ++i) {
        int gmB = m0 + wm + i * 16 + q * 4;
        float cr = cb, sr = sb;
#pragma unroll
        for (int r = 0; r < 4; ++r) {
          float v = acc[i][j][r];
          float p = __shfl_xor(v, 1);
          dst[(long)(gmB + r) * 1024 + c] = f2bf(v * cr + sgn * p * sr);
          float crn = cr * c1 - sr * s1;
          sr = sr * c1 + cr * s1;
          cr = crn;
        }
        float cbn = cb * c16 - sb * s16;
        sb = sb * c16 + cb * s16;
        cb = cbn;
      }
    }
  } else {
    // V: transpose to Vt[b][c][t]; 4 consecutive t per lane -> 8-B stores
    const int c0 = n0 - 2048;
#pragma unroll
    for (int j = 0; j < 4; ++j) {
      int c = c0 + wn + j * 16 + fm;
#pragma unroll
      for (int i = 0; i < 4; ++i) {
        int gmB = m0 + wm + i * 16 + q * 4;
        int b = gmB >> 11, t = gmB & 2047;
        ushort4 pk;
        pk.x = f2bf(acc[i][j][0]);
        pk.y = f2bf(acc[i][j][1]);
        pk.z = f2bf(acc[i][j][2]);
        pk.w = f2bf(acc[i][j][3]);
        *(ushort4*)&Vt[((long)b * 1024 + c) * 2048 + t] = pk;
      }
    }
  }
}

// ---------------------------------------------------------------------------
// E = exp(mask(Qr@Kr^T)/32) per batch (z), bf16, + rowsums. Compact triangular
// grid: 151 blocks/batch, decode (bm,bn) from linear idx (no no-op blocks).
__global__ __launch_bounds__(256, 3) void s_gemm(
    const unsigned short* __restrict__ Qr, const unsigned short* __restrict__ Kr,
    unsigned short* __restrict__ Sb, float* __restrict__ rowsums) {
  __shared__ __align__(16) unsigned short As[BM * BK];
  __shared__ __align__(16) unsigned short Bs[BN * BK];
  const int tid = threadIdx.x, lane = tid & 63, wave = tid >> 6;
  const int z = blockIdx.z;
  int idx = blockIdx.x, bm = 0;
#pragma unroll 1
  for (; bm < 16; ++bm) {  // counts per bm: min(bm+2,16); total 151
    int cnt = (bm + 2 > 16) ? 16 : bm + 2;
    if (idx < cnt) break;
    idx -= cnt;
  }
  const int bn = idx;
  const unsigned short* A = Qr + (long)z * 2048 * 1024;
  const unsigned short* B = Kr + (long)z * 2048 * 1024;
  unsigned short* S = Sb + (long)z * 2048 * 2048;
  float* rs = rowsums + (long)z * 2048;
  const int m0 = bm * BM, n0 = bn * BN;
  const int wm = (wave >> 1) * 64, wn = (wave & 1) * 64;
  const int q = lane >> 4, fm = lane & 15;

  f32x4 acc[4][4];
#pragma unroll
  for (int i = 0; i < 4; ++i)
#pragma unroll
    for (int j = 0; j < 4; ++j) acc[i][j] = (f32x4)(0.f);

  gemm_body(A, B, As, Bs, 1024, 1024, m0, n0, 16, tid, lane, wave, acc);

  // rowsum scratch overlays Bs (frag reads complete after the final barrier)
  float* rsum = (float*)Bs;
  __syncthreads();
  if (tid < 128) rsum[tid] = 0.f;
  __syncthreads();

#pragma unroll
  for (int i = 0; i < 4; ++i) {
    int gmB = m0 + wm + i * 16 + q * 4;
    float ps[4] = {0.f, 0.f, 0.f, 0.f};
#pragma unroll
    for (int j = 0; j < 4; ++j) {
      int gn = n0 + wn + j * 16 + fm;
#pragma unroll
      for (int r = 0; r < 4; ++r) {
        float e = (gn <= gmB + r + 1) ? __expf(acc[i][j][r] * 0.03125f) : 0.f;
        unsigned short h = f2bf(e);
        S[(long)(gmB + r) * 2048 + gn] = h;
        ps[r] += bf2f(h);  // sum the rounded value (matches stored E)
      }
    }
#pragma unroll
    for (int r = 0; r < 4; ++r) {
      float v = ps[r];
      v += __shfl_xor(v, 1);
      v += __shfl_xor(v, 2);
      v += __shfl_xor(v, 4);
      v += __shfl_xor(v, 8);
      if (fm == 0) atomicAdd(&rsum[wm + i * 16 + q * 4 + r], v);
    }
  }
  __syncthreads();
  if (tid < 128) atomicAdd(&rs[m0 + tid], rsum[tid]);
}

// ---------------------------------------------------------------------------
// out = (E @ Vt^T) / rowsum per batch (z), K-loop truncated causally.
// bm descending: longest-K blocks (diagonal) dispatch first (tail balance).
__global__ __launch_bounds__(256, 3) void pv_gemm(
    const unsigned short* __restrict__ Sb, const unsigned short* __restrict__ Vt,
    const float* __restrict__ rowsums, float* __restrict__ out, int b0) {
  __shared__ __align__(16) unsigned short As[BM * BK];
  __shared__ __align__(16) unsigned short Bs[BN * BK];
  const int tid = threadIdx.x, lane = tid & 63, wave = tid >> 6;
  const int bm = 15 - blockIdx.y, bn = blockIdx.x, z = blockIdx.z;
  const unsigned short* A = Sb + (long)z * 2048 * 2048;
  const unsigned short* B = Vt + (long)(b0 + z) * 1024 * 2048;
  const float* rs = rowsums + (long)(b0 + z) * 2048;
  float* C = out + (long)(b0 + z) * 2048 * 1024;
  int ktiles = 2 * bm + 3;  // keys valid up to q+1, q <= m0+127; BK=64
  if (ktiles > 32) ktiles = 32;
  const int m0 = bm * BM, n0 = bn * BN;
  const int wm = (wave >> 1) * 64, wn = (wave & 1) * 64;
  const int q = lane >> 4, fm = lane & 15;

  f32x4 acc[4][4];
#pragma unroll
  for (int i = 0; i < 4; ++i)
#pragma unroll
    for (int j = 0; j < 4; ++j) acc[i][j] = (f32x4)(0.f);

  gemm_body(A, B, As, Bs, 2048, 2048, m0, n0, ktiles, tid, lane, wave, acc);

#pragma unroll
  for (int i = 0; i < 4; ++i) {
    int gmB = m0 + wm + i * 16 + q * 4;
#pragma unroll
    for (int r = 0; r < 4; ++r) {
      float inv = 1.f / rs[gmB + r];
#pragma unroll
      for (int j = 0; j < 4; ++j) {
        int gn = n0 + wn + j * 16 + fm;
        C[(long)(gmB + r) * 1024 + gn] = acc[i][j][r] * inv;
      }
    }
  }
}

// ---------------------------------------------------------------------------
extern "C" void kernel_launch(void* const* d_in, const int* in_sizes, int n_in,
                              void* d_out, int out_size, void* d_ws, size_t ws_size,
                              hipStream_t stream) {
  const float* x = (const float*)d_in[0];
  const float* Wq = (const float*)d_in[1];
  const float* Wk = (const float*)d_in[2];
  const float* Wv = (const float*)d_in[3];
  float* out = (float*)d_out;

  // Layout: rowsums[32 KB] | Qr[16 MB] | Kr[16 MB] | Vt[16 MB] | xb[16 MB] |
  // Wb[6 MB]. E (bf16, 8 MB/batch) overlays xb/Wb (dead after qkv_rope_gemm).
  float* rowsums = (float*)d_ws;                      // [4][2048] fp32
  unsigned short* Qr = (unsigned short*)d_ws + 16384; // +32 KB
  unsigned short* Kr = Qr + (long)8192 * 1024;
  unsigned short* Vt = Kr + (long)8192 * 1024;        // [b][c][t]
  unsigned short* xb = Vt + (long)8192 * 1024;
  unsigned short* Wb = xb + (long)8192 * 1024;
  unsigned short* Sb = xb;                            // bf16 E, BCH x 2048 x 2048

  int BCH = 4;
  while (BCH > 1 && (size_t)32768 + (size_t)(48 + 8 * BCH) * 1024 * 1024 > ws_size)
    BCH >>= 1;

  cvt_all<<<11265, 256, 0, stream>>>((const float4*)x, (const float4*)Wq,
                                     (const float4*)Wk, (const float4*)Wv,
                                     (ushort4*)xb, (ushort4*)Wb, (float4*)rowsums);

  qkv_rope_gemm<<<dim3(64, 24), 256, 0, stream>>>(xb, Wb, Qr, Kr, Vt);

  for (int b0 = 0; b0 < 4; b0 += BCH) {
    s_gemm<<<dim3(151, 1, BCH), 256, 0, stream>>>(Qr + (long)b0 * 2048 * 1024,
                                                  Kr + (long)b0 * 2048 * 1024,
                                                  Sb, rowsums + (long)b0 * 2048);
    pv_gemm<<<dim3(8, 16, BCH), 256, 0, stream>>>(Sb, Vt, rowsums, out, b0);
  }
}